// Round 1
// baseline (289.831 us; speedup 1.0000x reference)
//
#include <hip/hip_runtime.h>

// MultiAttention fused pipeline for MI355X (gfx950).
// B=1, C=64, H=W=64 (N=4096), NH=8, DK=64, D=512.

#define N_TOK 4096
#define D_DIM 512

typedef __attribute__((ext_vector_type(8))) short bf16x8;
typedef __attribute__((ext_vector_type(4))) float f32x4;

__device__ __forceinline__ ushort f2bf(float x){
  uint u = __float_as_uint(x);
  u += 0x7fffu + ((u >> 16) & 1u);   // round-to-nearest-even
  return (ushort)(u >> 16);
}
__device__ __forceinline__ float bf2f(ushort h){
  return __uint_as_float(((uint)h) << 16);
}
__device__ __forceinline__ float gelu_(float x){
  return 0.5f * x * (1.0f + erff(x * 0.70710678118654752f));
}
__device__ __forceinline__ float sigmoid_(float x){
  return 1.0f / (1.0f + __expf(-x));
}
// XOR swizzle for row-major [R][64] bf16 LDS tiles (128B rows): element index.
__device__ __forceinline__ int SWZ(int r, int c){
  return r*64 + (((c>>3) ^ (r&7)) << 3) + (c&7);
}

// ---------------- K1: prep (x transpose to [n][c] bf16, weights -> bf16) ----
__global__ __launch_bounds__(256) void k_prep(const float* __restrict__ xin,
    const float* __restrict__ Wq, const float* __restrict__ Wk,
    const float* __restrict__ Wv, const float* __restrict__ Wout,
    ushort* __restrict__ xb, ushort* __restrict__ Wqb, ushort* __restrict__ Wkb,
    ushort* __restrict__ Wvb, ushort* __restrict__ Woutb){
  int i = blockIdx.x*256 + threadIdx.x;
  if (i < 262144){ int n = i >> 6, c = i & 63; xb[i] = f2bf(xin[c*4096 + n]); return; }
  i -= 262144;
  if (i < 32768){ Wqb[i] = f2bf(Wq[i]); return; }
  i -= 32768;
  if (i < 32768){ Wkb[i] = f2bf(Wk[i]); return; }
  i -= 32768;
  if (i < 32768){ Wvb[i] = f2bf(Wv[i]); return; }
  i -= 32768;
  if (i < 32768){ Woutb[i] = f2bf(Wout[i]); return; }
}

// ---------------- K2: QKV projection (MFMA) + cosine norm for q,k ----------
// grid (256, 3): 16 rows/block, z = 0:q 1:k 2:v. block 256 = 4 waves, each
// wave covers 128 output cols (2 heads).
__global__ __launch_bounds__(256) void k_qkv(const ushort* __restrict__ xb,
    const ushort* __restrict__ Wqb, const ushort* __restrict__ Wkb,
    const ushort* __restrict__ Wvb, ushort* __restrict__ q_bf,
    ushort* __restrict__ k_bf, ushort* __restrict__ v_bf, float* __restrict__ vT){
  const int z = blockIdx.y;
  const int n0 = blockIdx.x * 16;
  const int lane = threadIdx.x & 63, w = threadIdx.x >> 6;
  const int l15 = lane & 15, g = lane >> 4;
  const int obase = w * 128;
  const ushort* Wb = (z==0) ? Wqb : (z==1) ? Wkb : Wvb;
  const ushort* arow = xb + (size_t)(n0 + l15)*64;
  bf16x8 a0 = *(const bf16x8*)(arow + 8*g);
  bf16x8 a1 = *(const bf16x8*)(arow + 32 + 8*g);
  f32x4 acc[8];
#pragma unroll
  for (int t=0;t<8;t++) acc[t] = (f32x4){0.f,0.f,0.f,0.f};
#pragma unroll
  for (int t=0;t<8;t++){
    const ushort* brow = Wb + (size_t)(obase + 16*t + l15)*64;
    bf16x8 b0 = *(const bf16x8*)(brow + 8*g);
    bf16x8 b1 = *(const bf16x8*)(brow + 32 + 8*g);
    acc[t] = __builtin_amdgcn_mfma_f32_16x16x32_bf16(a0, b0, acc[t], 0,0,0);
    acc[t] = __builtin_amdgcn_mfma_f32_16x16x32_bf16(a1, b1, acc[t], 0,0,0);
  }
  if (z < 2){  // cosine normalization per (row, head): head = 64 consecutive cols
#pragma unroll
    for (int hh=0; hh<2; hh++){
#pragma unroll
      for (int r=0;r<4;r++){
        float ss = 0.f;
#pragma unroll
        for (int tt=0;tt<4;tt++){ float v = acc[hh*4+tt][r]; ss += v*v; }
        ss += __shfl_xor(ss, 1); ss += __shfl_xor(ss, 2);
        ss += __shfl_xor(ss, 4); ss += __shfl_xor(ss, 8);
        float inv = 1.0f / fmaxf(sqrtf(ss), 1e-12f);
#pragma unroll
        for (int tt=0;tt<4;tt++) acc[hh*4+tt][r] *= inv;
      }
    }
  }
  ushort* dst = (z==0) ? q_bf : (z==1) ? k_bf : v_bf;
#pragma unroll
  for (int t=0;t<8;t++){
    int col = obase + 16*t + l15;
#pragma unroll
    for (int r=0;r<4;r++){
      int row = n0 + 4*g + r;
      float val = acc[t][r];
      dst[(size_t)row*512 + col] = f2bf(val);
      if (z == 2) vT[(size_t)col*4096 + row] = val;
    }
  }
}

// ---------------- K3: flash attention (MFMA) + pooled accumulation ---------
// grid (64, 8): (q-block of 64 rows, head). block 256 = 4 waves, 16 rows/wave.
__global__ __launch_bounds__(256) void k_attn(const ushort* __restrict__ q_bf,
    const ushort* __restrict__ k_bf, const ushort* __restrict__ v_bf,
    const float* __restrict__ scale, ushort* __restrict__ att_bf,
    float* __restrict__ pooled){
  __shared__ ushort Kt[64*64];       // [key][d], swizzled
  __shared__ ushort Vt[64*64];       // [d][key], swizzled
  __shared__ ushort Pl[4*16*64];     // per-wave P tiles [row][key], swizzled
  const int h = blockIdx.y;
  const int qb = blockIdx.x;
  const int tid = threadIdx.x;
  const int lane = tid & 63, w = tid >> 6;
  const int l15 = lane & 15, g = lane >> 4;
  const float sc = scale[h];
  const int rowA = qb*64 + w*16 + l15;
  const ushort* qrow = q_bf + (size_t)rowA*512 + h*64;
  bf16x8 qa0 = *(const bf16x8*)(qrow + 8*g);
  bf16x8 qa1 = *(const bf16x8*)(qrow + 32 + 8*g);
  f32x4 O[4];
#pragma unroll
  for (int t=0;t<4;t++) O[t] = (f32x4){0.f,0.f,0.f,0.f};
  float m_r[4] = {-1e30f,-1e30f,-1e30f,-1e30f};
  float l_r[4] = {0.f,0.f,0.f,0.f};
  ushort* Pw = Pl + w*1024;

  for (int kv0 = 0; kv0 < 4096; kv0 += 64){
    { // stage K and V^T tiles (coalesced global reads)
      int key = tid >> 2;
      int d0 = (tid & 3) << 4;
      const ushort* ks = k_bf + (size_t)(kv0+key)*512 + h*64 + d0;
      const ushort* vs = v_bf + (size_t)(kv0+key)*512 + h*64 + d0;
      bf16x8 ka = *(const bf16x8*)ks;  bf16x8 kb = *(const bf16x8*)(ks+8);
      bf16x8 va = *(const bf16x8*)vs;  bf16x8 vb = *(const bf16x8*)(vs+8);
      *(bf16x8*)&Kt[SWZ(key, d0)]   = ka;
      *(bf16x8*)&Kt[SWZ(key, d0+8)] = kb;
#pragma unroll
      for (int i=0;i<8;i++){
        Vt[SWZ(d0+i,   key)] = (ushort)va[i];
        Vt[SWZ(d0+8+i, key)] = (ushort)vb[i];
      }
    }
    __syncthreads();
    // QK^T: S[16 rows][64 keys] as 4 tiles
    f32x4 S[4];
#pragma unroll
    for (int s=0;s<4;s++){
      int kr = 16*s + l15;
      bf16x8 b0 = *(const bf16x8*)&Kt[SWZ(kr, 8*g)];
      bf16x8 b1 = *(const bf16x8*)&Kt[SWZ(kr, 32 + 8*g)];
      f32x4 z4 = (f32x4){0.f,0.f,0.f,0.f};
      z4 = __builtin_amdgcn_mfma_f32_16x16x32_bf16(qa0, b0, z4, 0,0,0);
      z4 = __builtin_amdgcn_mfma_f32_16x16x32_bf16(qa1, b1, z4, 0,0,0);
      S[s] = z4 * sc;
    }
    // online softmax per row r = 4g+reg
#pragma unroll
    for (int r=0;r<4;r++){
      float mx = fmaxf(fmaxf(S[0][r],S[1][r]), fmaxf(S[2][r],S[3][r]));
      mx = fmaxf(mx, __shfl_xor(mx,1)); mx = fmaxf(mx, __shfl_xor(mx,2));
      mx = fmaxf(mx, __shfl_xor(mx,4)); mx = fmaxf(mx, __shfl_xor(mx,8));
      float mnew = fmaxf(m_r[r], mx);
      float alpha = __expf(m_r[r] - mnew);
      m_r[r] = mnew;
      float rs = 0.f;
#pragma unroll
      for (int s=0;s<4;s++){
        float p = __expf(S[s][r] - mnew);
        S[s][r] = p; rs += p;
      }
      rs += __shfl_xor(rs,1); rs += __shfl_xor(rs,2);
      rs += __shfl_xor(rs,4); rs += __shfl_xor(rs,8);
      l_r[r] = l_r[r]*alpha + rs;
#pragma unroll
      for (int t=0;t<4;t++) O[t][r] *= alpha;
#pragma unroll
      for (int s=0;s<4;s++) Pw[SWZ(4*g+r, 16*s+l15)] = f2bf(S[s][r]);
    }
    // PV: O += P @ V   (P and V both k-indexed 8g+i -> consistent)
    bf16x8 pa0 = *(const bf16x8*)&Pw[SWZ(l15, 8*g)];
    bf16x8 pa1 = *(const bf16x8*)&Pw[SWZ(l15, 32 + 8*g)];
#pragma unroll
    for (int t=0;t<4;t++){
      bf16x8 vb0 = *(const bf16x8*)&Vt[SWZ(16*t+l15, 8*g)];
      bf16x8 vb1 = *(const bf16x8*)&Vt[SWZ(16*t+l15, 32 + 8*g)];
      O[t] = __builtin_amdgcn_mfma_f32_16x16x32_bf16(pa0, vb0, O[t], 0,0,0);
      O[t] = __builtin_amdgcn_mfma_f32_16x16x32_bf16(pa1, vb1, O[t], 0,0,0);
    }
    __syncthreads();
  }
  float invl[4];
#pragma unroll
  for (int r=0;r<4;r++) invl[r] = 1.0f / l_r[r];
#pragma unroll
  for (int t=0;t<4;t++){
    float cs = 0.f;
#pragma unroll
    for (int r=0;r<4;r++){
      float val = O[t][r] * invl[r];
      att_bf[(size_t)(qb*64 + w*16 + 4*g + r)*512 + h*64 + 16*t + l15] = f2bf(val);
      cs += val;
    }
    cs += __shfl_xor(cs, 16); cs += __shfl_xor(cs, 32);
    if (g == 0) atomicAdd(&pooled[h*64 + 16*t + l15], cs);
  }
}

// ---------------- K4: depthwise 3x3 + bias + BN + GELU (f32) --------------
__global__ __launch_bounds__(256) void k_conv(const float* __restrict__ vT,
    const float* __restrict__ dw_w, const float* __restrict__ dw_b,
    const float* __restrict__ dw_g, const float* __restrict__ dw_bt,
    const float* __restrict__ dw_m, const float* __restrict__ dw_v,
    float* __restrict__ conv_x){
  __shared__ float tile[4096];
  const int d = blockIdx.x;
  const int tid = threadIdx.x;
  const float* src = vT + (size_t)d*4096;
#pragma unroll
  for (int i=0;i<16;i++) tile[tid + 256*i] = src[tid + 256*i];
  __syncthreads();
  float wv[9];
#pragma unroll
  for (int i=0;i<9;i++) wv[i] = dw_w[d*9+i];
  const float bias = dw_b[d];
  const float bnsc = dw_g[d] * rsqrtf(dw_v[d] + 1e-5f);
  const float bnb  = dw_bt[d] - dw_m[d]*bnsc;
  float* dst = conv_x + (size_t)d*4096;
#pragma unroll 4
  for (int i=0;i<16;i++){
    int p = tid + 256*i;
    int y = p >> 6, x = p & 63;
    float acc = 0.f;
#pragma unroll
    for (int ky=0;ky<3;ky++){
      int yy = y + ky - 1;
      if (yy < 0 || yy > 63) continue;
#pragma unroll
      for (int kx=0;kx<3;kx++){
        int xx = x + kx - 1;
        if (xx < 0 || xx > 63) continue;
        acc += wv[ky*3+kx] * tile[yy*64 + xx];
      }
    }
    float c = (acc + bias)*bnsc + bnb;
    dst[p] = gelu_(c);
  }
}

// ---------------- K5: spatial interaction -> sigmoid(sm)[n] ---------------
__global__ __launch_bounds__(256) void k_spatial(const float* __restrict__ conv_x,
    const float* __restrict__ si_w1, const float* __restrict__ si_b1,
    const float* __restrict__ si_g, const float* __restrict__ si_bt,
    const float* __restrict__ si_m, const float* __restrict__ si_v,
    const float* __restrict__ si_w2, const float* __restrict__ si_b2,
    float* __restrict__ sig_sm){
  __shared__ float red[16];
  const int n0 = blockIdx.x * 16;
  const int tid = threadIdx.x;
  const int nl = tid & 15;
  const int eg = tid >> 4;   // 0..15, two e's each
  const int n = n0 + nl;
  float a0 = 0.f, a1 = 0.f;
  const float* w1a = si_w1 + (size_t)(2*eg)*512;
  const float* w1b = w1a + 512;
#pragma unroll 4
  for (int d=0; d<512; d++){
    float x = conv_x[(size_t)d*4096 + n];
    a0 += w1a[d]*x;
    a1 += w1b[d]*x;
  }
  float outp = 0.f;
  {
    int e = 2*eg;
    float s = si_g[e] * rsqrtf(si_v[e] + 1e-5f);
    float v = (a0 + si_b1[e] - si_m[e]) * s + si_bt[e];
    outp += si_w2[e] * gelu_(v);
    e = 2*eg + 1;
    s = si_g[e] * rsqrtf(si_v[e] + 1e-5f);
    v = (a1 + si_b1[e] - si_m[e]) * s + si_bt[e];
    outp += si_w2[e] * gelu_(v);
  }
  if (tid < 16) red[tid] = 0.f;
  __syncthreads();
  atomicAdd(&red[nl], outp);
  __syncthreads();
  if (tid < 16) sig_sm[n0 + tid] = sigmoid_(red[tid] + si_b2[0]);
}

// ---------------- K6: channel interaction -> sigmoid(cm)[d] ---------------
__global__ __launch_bounds__(256) void k_channel(const float* __restrict__ pooled,
    const float* __restrict__ ci_w1, const float* __restrict__ ci_b1,
    const float* __restrict__ ci_w2, const float* __restrict__ ci_b2,
    float* __restrict__ sig_cm){
  __shared__ float pl[512];
  __shared__ float h1[128];
  const int tid = threadIdx.x;
  pl[tid]       = pooled[tid]       * (1.0f/4096.0f);
  pl[tid + 256] = pooled[tid + 256] * (1.0f/4096.0f);
  __syncthreads();
  if (tid < 128){
    float acc = ci_b1[tid];
    const float* wr = ci_w1 + (size_t)tid*512;
#pragma unroll 4
    for (int c=0;c<512;c++) acc += wr[c]*pl[c];
    h1[tid] = gelu_(acc);
  }
  __syncthreads();
#pragma unroll
  for (int dd=0; dd<2; dd++){
    int d = tid + 256*dd;
    float acc = ci_b2[d];
    const float* wr = ci_w2 + (size_t)d*128;
#pragma unroll 4
    for (int e=0;e<128;e++) acc += wr[e]*h1[e];
    sig_cm[d] = sigmoid_(acc);
  }
}

// ---------------- K8: generic depthwise 3x3 on 64x64 (embed branch) -------
__global__ __launch_bounds__(256) void k_dwconv64(const float* __restrict__ in,
    const float* __restrict__ w9, float* __restrict__ out, int do_gelu){
  __shared__ float tile[4096];
  const int c = blockIdx.x;
  const int tid = threadIdx.x;
  const float* src = in + (size_t)c*4096;
#pragma unroll
  for (int i=0;i<16;i++) tile[tid + 256*i] = src[tid + 256*i];
  __syncthreads();
  float wv[9];
#pragma unroll
  for (int i=0;i<9;i++) wv[i] = w9[c*9+i];
  float* dst = out + (size_t)c*4096;
#pragma unroll 4
  for (int i=0;i<16;i++){
    int p = tid + 256*i;
    int y = p >> 6, x = p & 63;
    float acc = 0.f;
#pragma unroll
    for (int ky=0;ky<3;ky++){
      int yy = y + ky - 1;
      if (yy < 0 || yy > 63) continue;
#pragma unroll
      for (int kx=0;kx<3;kx++){
        int xx = x + kx - 1;
        if (xx < 0 || xx > 63) continue;
        acc += wv[ky*3+kx] * tile[yy*64 + xx];
      }
    }
    dst[p] = do_gelu ? gelu_(acc) : acc;
  }
}

// ---------------- K7: gate fuse + output GEMM + embed add -----------------
// grid 256, block 64 (1 wave): 16 rows x 64 out-cols per wave.
__global__ __launch_bounds__(64) void k_final(const ushort* __restrict__ att_bf,
    const float* __restrict__ conv_x, const float* __restrict__ sig_sm,
    const float* __restrict__ sig_cm, const ushort* __restrict__ Woutb,
    const float* __restrict__ bout, const float* __restrict__ embed,
    float* __restrict__ out){
  const int lane = threadIdx.x;
  const int l15 = lane & 15, g = lane >> 4;
  const int n0 = blockIdx.x * 16;
  const int rowA = n0 + l15;
  const float srow = sig_sm[rowA];
  f32x4 acc[4];
#pragma unroll
  for (int t=0;t<4;t++) acc[t] = (f32x4){0.f,0.f,0.f,0.f};
#pragma unroll 2
  for (int kk=0;kk<16;kk++){
    int k0 = kk*32;
    bf16x8 at8 = *(const bf16x8*)(att_bf + (size_t)rowA*512 + k0 + 8*g);
    bf16x8 af;
#pragma unroll
    for (int i=0;i<8;i++){
      int d = k0 + 8*g + i;
      float zv = bf2f((ushort)at8[i]) * srow + conv_x[(size_t)d*4096 + rowA] * sig_cm[d];
      af[i] = (short)f2bf(zv);
    }
#pragma unroll
    for (int t=0;t<4;t++){
      bf16x8 bf8 = *(const bf16x8*)(Woutb + (size_t)(16*t+l15)*512 + k0 + 8*g);
      acc[t] = __builtin_amdgcn_mfma_f32_16x16x32_bf16(af, bf8, acc[t], 0,0,0);
    }
  }
#pragma unroll
  for (int t=0;t<4;t++){
    int o = 16*t + l15;
    float bo = bout[o];
#pragma unroll
    for (int r=0;r<4;r++){
      int row = n0 + 4*g + r;
      size_t idx = (size_t)row*64 + o;
      out[idx] = acc[t][r] + bo + embed[idx];
    }
  }
}

extern "C" void kernel_launch(void* const* d_in, const int* in_sizes, int n_in,
                              void* d_out, int out_size, void* d_ws, size_t ws_size,
                              hipStream_t stream){
  (void)in_sizes; (void)n_in; (void)out_size; (void)ws_size;
  const float* x_in  = (const float*)d_in[0];
  const float* Wq    = (const float*)d_in[1];
  const float* Wk    = (const float*)d_in[2];
  const float* Wv    = (const float*)d_in[3];
  const float* scale = (const float*)d_in[4];
  const float* Wout  = (const float*)d_in[5];
  const float* bout  = (const float*)d_in[6];
  const float* dw_w  = (const float*)d_in[7];
  const float* dw_b  = (const float*)d_in[8];
  const float* dw_g  = (const float*)d_in[9];
  const float* dw_bt = (const float*)d_in[10];
  const float* dw_m  = (const float*)d_in[11];
  const float* dw_v  = (const float*)d_in[12];
  const float* ci_w1 = (const float*)d_in[13];
  const float* ci_b1 = (const float*)d_in[14];
  const float* ci_w2 = (const float*)d_in[15];
  const float* ci_b2 = (const float*)d_in[16];
  const float* si_w1 = (const float*)d_in[17];
  const float* si_b1 = (const float*)d_in[18];
  const float* si_g  = (const float*)d_in[19];
  const float* si_bt = (const float*)d_in[20];
  const float* si_m  = (const float*)d_in[21];
  const float* si_v  = (const float*)d_in[22];
  const float* si_w2 = (const float*)d_in[23];
  const float* si_b2 = (const float*)d_in[24];
  const float* pe_w1 = (const float*)d_in[25];
  const float* pe_w2 = (const float*)d_in[26];
  float* out = (float*)d_out;

  char* p = (char*)d_ws;
  auto alloc = [&](size_t bytes)->char*{
    char* r = p; p += (bytes + 255) & ~(size_t)255; return r;
  };
  ushort* xb     = (ushort*)alloc(262144*sizeof(ushort));
  ushort* Wqb    = (ushort*)alloc(32768*sizeof(ushort));
  ushort* Wkb    = (ushort*)alloc(32768*sizeof(ushort));
  ushort* Wvb    = (ushort*)alloc(32768*sizeof(ushort));
  ushort* Woutb  = (ushort*)alloc(32768*sizeof(ushort));
  ushort* q_bf   = (ushort*)alloc((size_t)4096*512*sizeof(ushort));
  ushort* k_bf   = (ushort*)alloc((size_t)4096*512*sizeof(ushort));
  ushort* v_bf   = (ushort*)alloc((size_t)4096*512*sizeof(ushort));
  float*  vT     = (float*) alloc((size_t)512*4096*sizeof(float));
  ushort* att_bf = (ushort*)alloc((size_t)4096*512*sizeof(ushort));
  float*  conv_x = (float*) alloc((size_t)512*4096*sizeof(float));
  float*  t1     = (float*) alloc((size_t)64*4096*sizeof(float));
  float*  embed  = (float*) alloc((size_t)64*4096*sizeof(float));
  float*  pooled = (float*) alloc(512*sizeof(float));
  float*  sig_sm = (float*) alloc(4096*sizeof(float));
  float*  sig_cm = (float*) alloc(512*sizeof(float));

  k_prep<<<1536, 256, 0, stream>>>(x_in, Wq, Wk, Wv, Wout, xb, Wqb, Wkb, Wvb, Woutb);
  k_qkv<<<dim3(256,3), 256, 0, stream>>>(xb, Wqb, Wkb, Wvb, q_bf, k_bf, v_bf, vT);
  hipMemsetAsync(pooled, 0, 512*sizeof(float), stream);
  k_attn<<<dim3(64,8), 256, 0, stream>>>(q_bf, k_bf, v_bf, scale, att_bf, pooled);
  k_conv<<<512, 256, 0, stream>>>(vT, dw_w, dw_b, dw_g, dw_bt, dw_m, dw_v, conv_x);
  k_spatial<<<256, 256, 0, stream>>>(conv_x, si_w1, si_b1, si_g, si_bt, si_m, si_v,
                                     si_w2, si_b2, sig_sm);
  k_channel<<<1, 256, 0, stream>>>(pooled, ci_w1, ci_b1, ci_w2, ci_b2, sig_cm);
  k_dwconv64<<<64, 256, 0, stream>>>(x_in, pe_w1, t1, 1);
  k_dwconv64<<<64, 256, 0, stream>>>(t1, pe_w2, embed, 0);
  k_final<<<256, 64, 0, stream>>>(att_bf, conv_x, sig_sm, sig_cm, Woutb, bout, embed, out);
}

// Round 2
// 200.955 us; speedup vs baseline: 1.4423x; 1.4423x over previous
//
#include <hip/hip_runtime.h>

// MultiAttention fused pipeline for MI355X (gfx950).
// B=1, C=64, H=W=64 (N=4096), NH=8, DK=64, D=512.

#define LOG2E 1.442695040888963f

typedef __attribute__((ext_vector_type(8))) short bf16x8;
typedef __attribute__((ext_vector_type(4))) float f32x4;
typedef __attribute__((ext_vector_type(4))) int i32x4;
typedef __attribute__((ext_vector_type(2))) int i32x2;
typedef __attribute__((ext_vector_type(4))) ushort u16x4;

__device__ __forceinline__ ushort f2bf(float x){
  uint u = __float_as_uint(x);
  u += 0x7fffu + ((u >> 16) & 1u);   // round-to-nearest-even
  return (ushort)(u >> 16);
}
__device__ __forceinline__ float bf2f(ushort h){
  return __uint_as_float(((uint)h) << 16);
}
__device__ __forceinline__ float gelu_(float x){
  return 0.5f * x * (1.0f + erff(x * 0.70710678118654752f));
}
__device__ __forceinline__ float sigmoid_(float x){
  return 1.0f / (1.0f + __expf(-x));
}
__device__ __forceinline__ float exp2_(float x){
  float r; asm("v_exp_f32 %0, %1" : "=v"(r) : "v"(x)); return r;
}
__device__ __forceinline__ int cvtpk(float lo, float hi){
  int r; asm("v_cvt_pk_bf16_f32 %0, %1, %2" : "=v"(r) : "v"(lo), "v"(hi)); return r;
}

// ---------------- K1: prep (x transpose to [n][c] bf16, weights -> bf16) ----
__global__ __launch_bounds__(256) void k_prep(const float* __restrict__ xin,
    const float* __restrict__ Wq, const float* __restrict__ Wk,
    const float* __restrict__ Wv, const float* __restrict__ Wout,
    ushort* __restrict__ xb, ushort* __restrict__ Wqb, ushort* __restrict__ Wkb,
    ushort* __restrict__ Wvb, ushort* __restrict__ Woutb){
  int i = blockIdx.x*256 + threadIdx.x;
  if (i < 262144){ int n = i >> 6, c = i & 63; xb[i] = f2bf(xin[c*4096 + n]); return; }
  i -= 262144;
  if (i < 32768){ Wqb[i] = f2bf(Wq[i]); return; }
  i -= 32768;
  if (i < 32768){ Wkb[i] = f2bf(Wk[i]); return; }
  i -= 32768;
  if (i < 32768){ Wvb[i] = f2bf(Wv[i]); return; }
  i -= 32768;
  if (i < 32768){ Woutb[i] = f2bf(Wout[i]); return; }
}

// ---------------- K2: QKV projection (MFMA) + cosine norm for q,k ----------
// grid (256, 3): 16 rows/block, z = 0:q 1:k 2:v. block 256 = 4 waves, each
// wave covers 128 output cols (2 heads). q gets scale*log2e folded in.
__global__ __launch_bounds__(256) void k_qkv(const ushort* __restrict__ xb,
    const ushort* __restrict__ Wqb, const ushort* __restrict__ Wkb,
    const ushort* __restrict__ Wvb, const float* __restrict__ scale,
    ushort* __restrict__ q_bf, ushort* __restrict__ k_bf, ushort* __restrict__ vT){
  const int z = blockIdx.y;
  const int n0 = blockIdx.x * 16;
  const int lane = threadIdx.x & 63, w = threadIdx.x >> 6;
  const int l15 = lane & 15, g = lane >> 4;
  const int obase = w * 128;
  const ushort* Wb = (z==0) ? Wqb : (z==1) ? Wkb : Wvb;
  const ushort* arow = xb + (size_t)(n0 + l15)*64;
  bf16x8 a0 = *(const bf16x8*)(arow + 8*g);
  bf16x8 a1 = *(const bf16x8*)(arow + 32 + 8*g);
  f32x4 acc[8];
#pragma unroll
  for (int t=0;t<8;t++) acc[t] = (f32x4){0.f,0.f,0.f,0.f};
#pragma unroll
  for (int t=0;t<8;t++){
    const ushort* brow = Wb + (size_t)(obase + 16*t + l15)*64;
    bf16x8 b0 = *(const bf16x8*)(brow + 8*g);
    bf16x8 b1 = *(const bf16x8*)(brow + 32 + 8*g);
    acc[t] = __builtin_amdgcn_mfma_f32_16x16x32_bf16(a0, b0, acc[t], 0,0,0);
    acc[t] = __builtin_amdgcn_mfma_f32_16x16x32_bf16(a1, b1, acc[t], 0,0,0);
  }
  if (z < 2){  // cosine normalization per (row, head); head = 64 consecutive cols
#pragma unroll
    for (int hh=0; hh<2; hh++){
      float sfac = (z==0) ? (scale[2*w+hh] * LOG2E) : 1.0f;
#pragma unroll
      for (int r=0;r<4;r++){
        float ss = 0.f;
#pragma unroll
        for (int tt=0;tt<4;tt++){ float v = acc[hh*4+tt][r]; ss += v*v; }
        ss += __shfl_xor(ss, 1); ss += __shfl_xor(ss, 2);
        ss += __shfl_xor(ss, 4); ss += __shfl_xor(ss, 8);
        float inv = sfac / fmaxf(sqrtf(ss), 1e-12f);
#pragma unroll
        for (int tt=0;tt<4;tt++) acc[hh*4+tt][r] *= inv;
      }
    }
    ushort* dst = (z==0) ? q_bf : k_bf;
#pragma unroll
    for (int t=0;t<8;t++){
      int col = obase + 16*t + l15;
#pragma unroll
      for (int r=0;r<4;r++)
        dst[(size_t)(n0 + 4*g + r)*512 + col] = f2bf(acc[t][r]);
    }
  } else {
    // v: store transposed bf16 [d][n] (serves attention staging AND conv branch)
#pragma unroll
    for (int t=0;t<8;t++){
      int col = obase + 16*t + l15;
      u16x4 vs;
#pragma unroll
      for (int r=0;r<4;r++) vs[r] = f2bf(acc[t][r]);
      *(u16x4*)(vT + (size_t)col*4096 + n0 + 4*g) = vs;
    }
  }
}

// ---------------- K3: flash attention (swapped QK^T, no-max softmax) -------
// grid (64, 8): (q-block of 64 rows, head). block 256 = 4 waves, 16 rows/wave.
// Key insight: scores are cosine-normalized * scale(=1) -> bounded by 1, so
// softmax needs no max subtraction. Swapped QK^T (A=K, B=Q) puts P values
// exactly in the PV A-fragment layout: zero cross-lane ops.
__global__ __launch_bounds__(256) void k_attn(const ushort* __restrict__ q_bf,
    const ushort* __restrict__ k_bf, const ushort* __restrict__ vT,
    ushort* __restrict__ att_bf, float* __restrict__ pooled){
  __shared__ ushort Kt[2][4096];   // [key][d], XOR-swizzled 16B blocks
  __shared__ ushort Vt[2][4096];   // [d][key], XOR-swizzled 16B blocks
  const int h = blockIdx.y, qb = blockIdx.x;
  const int tid = threadIdx.x;
  const int lane = tid & 63, w = tid >> 6;
  const int l15 = lane & 15, g = lane >> 4;

  // staging assignment: 256 threads, each 32B of K and 32B of V per tile
  const int srow = tid >> 2, sb = tid & 3;
  const ushort* gK = k_bf + (size_t)srow*512 + h*64 + sb*8;
  const ushort* gV = vT + (size_t)(h*64 + srow)*4096 + sb*8;
  const int wOffA = srow*64 + ((sb ^ (srow & 7)) << 3);
  const int wOffB = srow*64 + (((sb + 4) ^ (srow & 7)) << 3);

  // q fragment (pre-scaled by scale*log2e)
  const int rowA = qb*64 + w*16 + l15;
  const ushort* qrow = q_bf + (size_t)rowA*512 + h*64;
  bf16x8 qa0 = *(const bf16x8*)(qrow + 8*g);
  bf16x8 qa1 = *(const bf16x8*)(qrow + 32 + 8*g);

  // per-lane LDS read offsets (elements)
  const int l7 = l15 & 7;
  const int kOff0 = l15*64 + ((g ^ l7) << 3);
  const int kOff1 = l15*64 + (((g + 4) ^ l7) << 3);
  const int g2 = g >> 1, gh = (g & 1) << 2;
  const int vOff0 = l15*64 + ((g2 ^ l7) << 3) + gh;          // keys 4g+0..3
  const int vOff1 = l15*64 + (((2 + g2) ^ l7) << 3) + gh;    // keys 16+4g..
  const int vOff2 = l15*64 + (((4 + g2) ^ l7) << 3) + gh;    // keys 32+4g..
  const int vOff3 = l15*64 + (((6 + g2) ^ l7) << 3) + gh;    // keys 48+4g..

  f32x4 O[4];
#pragma unroll
  for (int t=0;t<4;t++) O[t] = (f32x4){0.f,0.f,0.f,0.f};
  float lsum = 0.f;

  i32x4 pK0 = *(const i32x4*)gK;
  i32x4 pK1 = *(const i32x4*)(gK + 32);
  i32x4 pV0 = *(const i32x4*)gV;
  i32x4 pV1 = *(const i32x4*)(gV + 32);

  for (int it = 0; it < 64; ++it){
    ushort* Kb = Kt[it & 1];
    ushort* Vb = Vt[it & 1];
    *(i32x4*)(Kb + wOffA) = pK0;
    *(i32x4*)(Kb + wOffB) = pK1;
    *(i32x4*)(Vb + wOffA) = pV0;
    *(i32x4*)(Vb + wOffB) = pV1;
    __syncthreads();
    if (it < 63){
      gK += 64*512; gV += 64;
      pK0 = *(const i32x4*)gK;
      pK1 = *(const i32x4*)(gK + 32);
      pV0 = *(const i32x4*)gV;
      pV1 = *(const i32x4*)(gV + 32);
    }
    // S^T tiles: rows=key(16s+4g+r), cols=q(l15); p = exp2(S) (scale folded)
    float p[4][4];
#pragma unroll
    for (int s=0;s<4;s++){
      bf16x8 kf0 = *(const bf16x8*)(Kb + s*1024 + kOff0);
      bf16x8 kf1 = *(const bf16x8*)(Kb + s*1024 + kOff1);
      f32x4 st = (f32x4){0.f,0.f,0.f,0.f};
      st = __builtin_amdgcn_mfma_f32_16x16x32_bf16(kf0, qa0, st, 0,0,0);
      st = __builtin_amdgcn_mfma_f32_16x16x32_bf16(kf1, qa1, st, 0,0,0);
#pragma unroll
      for (int r=0;r<4;r++){ float e = exp2_(st[r]); p[s][r] = e; lsum += e; }
    }
    // pack PV A-fragments in-register: a0 elem i = p[i>>2][i&3] (key 16*(i>>2)+4g+(i&3))
    i32x4 A0, A1;
    A0[0]=cvtpk(p[0][0],p[0][1]); A0[1]=cvtpk(p[0][2],p[0][3]);
    A0[2]=cvtpk(p[1][0],p[1][1]); A0[3]=cvtpk(p[1][2],p[1][3]);
    A1[0]=cvtpk(p[2][0],p[2][1]); A1[1]=cvtpk(p[2][2],p[2][3]);
    A1[2]=cvtpk(p[3][0],p[3][1]); A1[3]=cvtpk(p[3][2],p[3][3]);
    union { i32x4 i; bf16x8 v; } ua0, ua1; ua0.i = A0; ua1.i = A1;
#pragma unroll
    for (int t=0;t<4;t++){
      const ushort* Vr = Vb + t*1024;
      union { bf16x8 v; i32x2 h[2]; } uv0, uv1;
      uv0.h[0] = *(const i32x2*)(Vr + vOff0);
      uv0.h[1] = *(const i32x2*)(Vr + vOff1);
      uv1.h[0] = *(const i32x2*)(Vr + vOff2);
      uv1.h[1] = *(const i32x2*)(Vr + vOff3);
      O[t] = __builtin_amdgcn_mfma_f32_16x16x32_bf16(ua0.v, uv0.v, O[t], 0,0,0);
      O[t] = __builtin_amdgcn_mfma_f32_16x16x32_bf16(ua1.v, uv1.v, O[t], 0,0,0);
    }
  }
  // softmax denominator: reduce per-lane partial sums across g-groups
  lsum += __shfl_xor(lsum, 16);
  lsum += __shfl_xor(lsum, 32);
  float invl[4];
#pragma unroll
  for (int r=0;r<4;r++) invl[r] = 1.0f / __shfl(lsum, 4*g + r);
#pragma unroll
  for (int t=0;t<4;t++){
    float cs = 0.f;
#pragma unroll
    for (int r=0;r<4;r++){
      float val = O[t][r] * invl[r];
      att_bf[(size_t)(qb*64 + w*16 + 4*g + r)*512 + h*64 + 16*t + l15] = f2bf(val);
      cs += val;
    }
    cs += __shfl_xor(cs, 16); cs += __shfl_xor(cs, 32);
    if (g == 0) atomicAdd(&pooled[h*64 + 16*t + l15], cs);
  }
}

// ---------------- K4: depthwise 3x3 + bias + BN + GELU (bf16 in, f32 out) --
__global__ __launch_bounds__(256) void k_conv(const ushort* __restrict__ vT,
    const float* __restrict__ dw_w, const float* __restrict__ dw_b,
    const float* __restrict__ dw_g, const float* __restrict__ dw_bt,
    const float* __restrict__ dw_m, const float* __restrict__ dw_v,
    float* __restrict__ conv_x){
  __shared__ float tile[4096];
  const int d = blockIdx.x;
  const int tid = threadIdx.x;
  const ushort* src = vT + (size_t)d*4096;
  {
    bf16x8 a = *(const bf16x8*)(src + tid*16);
    bf16x8 b = *(const bf16x8*)(src + tid*16 + 8);
#pragma unroll
    for (int j=0;j<8;j++){
      tile[tid*16 + j]     = bf2f((ushort)a[j]);
      tile[tid*16 + 8 + j] = bf2f((ushort)b[j]);
    }
  }
  __syncthreads();
  float wv[9];
#pragma unroll
  for (int i=0;i<9;i++) wv[i] = dw_w[d*9+i];
  const float bias = dw_b[d];
  const float bnsc = dw_g[d] * rsqrtf(dw_v[d] + 1e-5f);
  const float bnb  = dw_bt[d] - dw_m[d]*bnsc;
  float* dst = conv_x + (size_t)d*4096;
#pragma unroll 4
  for (int i=0;i<16;i++){
    int p = tid + 256*i;
    int y = p >> 6, x = p & 63;
    float acc = 0.f;
#pragma unroll
    for (int ky=0;ky<3;ky++){
      int yy = y + ky - 1;
      if (yy < 0 || yy > 63) continue;
#pragma unroll
      for (int kx=0;kx<3;kx++){
        int xx = x + kx - 1;
        if (xx < 0 || xx > 63) continue;
        acc += wv[ky*3+kx] * tile[yy*64 + xx];
      }
    }
    float c = (acc + bias)*bnsc + bnb;
    dst[p] = gelu_(c);
  }
}

// ---------------- K5: spatial interaction -> sigmoid(sm)[n] ---------------
__global__ __launch_bounds__(256) void k_spatial(const float* __restrict__ conv_x,
    const float* __restrict__ si_w1, const float* __restrict__ si_b1,
    const float* __restrict__ si_g, const float* __restrict__ si_bt,
    const float* __restrict__ si_m, const float* __restrict__ si_v,
    const float* __restrict__ si_w2, const float* __restrict__ si_b2,
    float* __restrict__ sig_sm){
  __shared__ float red[16];
  const int n0 = blockIdx.x * 16;
  const int tid = threadIdx.x;
  const int nl = tid & 15;
  const int eg = tid >> 4;   // 0..15, two e's each
  const int n = n0 + nl;
  float a0 = 0.f, a1 = 0.f;
  const float* w1a = si_w1 + (size_t)(2*eg)*512;
  const float* w1b = w1a + 512;
#pragma unroll 4
  for (int d=0; d<512; d++){
    float x = conv_x[(size_t)d*4096 + n];
    a0 += w1a[d]*x;
    a1 += w1b[d]*x;
  }
  float outp = 0.f;
  {
    int e = 2*eg;
    float s = si_g[e] * rsqrtf(si_v[e] + 1e-5f);
    float v = (a0 + si_b1[e] - si_m[e]) * s + si_bt[e];
    outp += si_w2[e] * gelu_(v);
    e = 2*eg + 1;
    s = si_g[e] * rsqrtf(si_v[e] + 1e-5f);
    v = (a1 + si_b1[e] - si_m[e]) * s + si_bt[e];
    outp += si_w2[e] * gelu_(v);
  }
  if (tid < 16) red[tid] = 0.f;
  __syncthreads();
  atomicAdd(&red[nl], outp);
  __syncthreads();
  if (tid < 16) sig_sm[n0 + tid] = sigmoid_(red[tid] + si_b2[0]);
}

// ---------------- K6: channel interaction -> sigmoid(cm)[d] ---------------
__global__ __launch_bounds__(256) void k_channel(const float* __restrict__ pooled,
    const float* __restrict__ ci_w1, const float* __restrict__ ci_b1,
    const float* __restrict__ ci_w2, const float* __restrict__ ci_b2,
    float* __restrict__ sig_cm){
  __shared__ float pl[512];
  __shared__ float h1[128];
  const int tid = threadIdx.x;
  pl[tid]       = pooled[tid]       * (1.0f/4096.0f);
  pl[tid + 256] = pooled[tid + 256] * (1.0f/4096.0f);
  __syncthreads();
  if (tid < 128){
    float acc = ci_b1[tid];
    const float* wr = ci_w1 + (size_t)tid*512;
#pragma unroll 4
    for (int c=0;c<512;c++) acc += wr[c]*pl[c];
    h1[tid] = gelu_(acc);
  }
  __syncthreads();
#pragma unroll
  for (int dd=0; dd<2; dd++){
    int d = tid + 256*dd;
    float acc = ci_b2[d];
    const float* wr = ci_w2 + (size_t)d*128;
#pragma unroll 4
    for (int e=0;e<128;e++) acc += wr[e]*h1[e];
    sig_cm[d] = sigmoid_(acc);
  }
}

// ---------------- K8: generic depthwise 3x3 on 64x64 (embed branch) -------
__global__ __launch_bounds__(256) void k_dwconv64(const float* __restrict__ in,
    const float* __restrict__ w9, float* __restrict__ out, int do_gelu){
  __shared__ float tile[4096];
  const int c = blockIdx.x;
  const int tid = threadIdx.x;
  const float* src = in + (size_t)c*4096;
#pragma unroll
  for (int i=0;i<16;i++) tile[tid + 256*i] = src[tid + 256*i];
  __syncthreads();
  float wv[9];
#pragma unroll
  for (int i=0;i<9;i++) wv[i] = w9[c*9+i];
  float* dst = out + (size_t)c*4096;
#pragma unroll 4
  for (int i=0;i<16;i++){
    int p = tid + 256*i;
    int y = p >> 6, x = p & 63;
    float acc = 0.f;
#pragma unroll
    for (int ky=0;ky<3;ky++){
      int yy = y + ky - 1;
      if (yy < 0 || yy > 63) continue;
#pragma unroll
      for (int kx=0;kx<3;kx++){
        int xx = x + kx - 1;
        if (xx < 0 || xx > 63) continue;
        acc += wv[ky*3+kx] * tile[yy*64 + xx];
      }
    }
    dst[p] = do_gelu ? gelu_(acc) : acc;
  }
}

// ---------------- K7: gate fuse + output GEMM + embed add -----------------
// grid 256, block 64 (1 wave): 16 rows x 64 out-cols per wave.
__global__ __launch_bounds__(64) void k_final(const ushort* __restrict__ att_bf,
    const float* __restrict__ conv_x, const float* __restrict__ sig_sm,
    const float* __restrict__ sig_cm, const ushort* __restrict__ Woutb,
    const float* __restrict__ bout, const float* __restrict__ embed,
    float* __restrict__ out){
  const int lane = threadIdx.x;
  const int l15 = lane & 15, g = lane >> 4;
  const int n0 = blockIdx.x * 16;
  const int rowA = n0 + l15;
  const float srow = sig_sm[rowA];
  f32x4 acc[4];
#pragma unroll
  for (int t=0;t<4;t++) acc[t] = (f32x4){0.f,0.f,0.f,0.f};
#pragma unroll 2
  for (int kk=0;kk<16;kk++){
    int k0 = kk*32;
    bf16x8 at8 = *(const bf16x8*)(att_bf + (size_t)rowA*512 + k0 + 8*g);
    bf16x8 af;
#pragma unroll
    for (int i=0;i<8;i++){
      int d = k0 + 8*g + i;
      float zv = bf2f((ushort)at8[i]) * srow + conv_x[(size_t)d*4096 + rowA] * sig_cm[d];
      af[i] = (short)f2bf(zv);
    }
#pragma unroll
    for (int t=0;t<4;t++){
      bf16x8 bf8 = *(const bf16x8*)(Woutb + (size_t)(16*t+l15)*512 + k0 + 8*g);
      acc[t] = __builtin_amdgcn_mfma_f32_16x16x32_bf16(af, bf8, acc[t], 0,0,0);
    }
  }
#pragma unroll
  for (int t=0;t<4;t++){
    int o = 16*t + l15;
    float bo = bout[o];
#pragma unroll
    for (int r=0;r<4;r++){
      int row = n0 + 4*g + r;
      size_t idx = (size_t)row*64 + o;
      out[idx] = acc[t][r] + bo + embed[idx];
    }
  }
}

extern "C" void kernel_launch(void* const* d_in, const int* in_sizes, int n_in,
                              void* d_out, int out_size, void* d_ws, size_t ws_size,
                              hipStream_t stream){
  (void)in_sizes; (void)n_in; (void)out_size; (void)ws_size;
  const float* x_in  = (const float*)d_in[0];
  const float* Wq    = (const float*)d_in[1];
  const float* Wk    = (const float*)d_in[2];
  const float* Wv    = (const float*)d_in[3];
  const float* scale = (const float*)d_in[4];
  const float* Wout  = (const float*)d_in[5];
  const float* bout  = (const float*)d_in[6];
  const float* dw_w  = (const float*)d_in[7];
  const float* dw_b  = (const float*)d_in[8];
  const float* dw_g  = (const float*)d_in[9];
  const float* dw_bt = (const float*)d_in[10];
  const float* dw_m  = (const float*)d_in[11];
  const float* dw_v  = (const float*)d_in[12];
  const float* ci_w1 = (const float*)d_in[13];
  const float* ci_b1 = (const float*)d_in[14];
  const float* ci_w2 = (const float*)d_in[15];
  const float* ci_b2 = (const float*)d_in[16];
  const float* si_w1 = (const float*)d_in[17];
  const float* si_b1 = (const float*)d_in[18];
  const float* si_g  = (const float*)d_in[19];
  const float* si_bt = (const float*)d_in[20];
  const float* si_m  = (const float*)d_in[21];
  const float* si_v  = (const float*)d_in[22];
  const float* si_w2 = (const float*)d_in[23];
  const float* si_b2 = (const float*)d_in[24];
  const float* pe_w1 = (const float*)d_in[25];
  const float* pe_w2 = (const float*)d_in[26];
  float* out = (float*)d_out;

  char* p = (char*)d_ws;
  auto alloc = [&](size_t bytes)->char*{
    char* r = p; p += (bytes + 255) & ~(size_t)255; return r;
  };
  ushort* xb     = (ushort*)alloc(262144*sizeof(ushort));
  ushort* Wqb    = (ushort*)alloc(32768*sizeof(ushort));
  ushort* Wkb    = (ushort*)alloc(32768*sizeof(ushort));
  ushort* Wvb    = (ushort*)alloc(32768*sizeof(ushort));
  ushort* Woutb  = (ushort*)alloc(32768*sizeof(ushort));
  ushort* q_bf   = (ushort*)alloc((size_t)4096*512*sizeof(ushort));
  ushort* k_bf   = (ushort*)alloc((size_t)4096*512*sizeof(ushort));
  ushort* vTb    = (ushort*)alloc((size_t)512*4096*sizeof(ushort));
  ushort* att_bf = (ushort*)alloc((size_t)4096*512*sizeof(ushort));
  float*  conv_x = (float*) alloc((size_t)512*4096*sizeof(float));
  float*  t1     = (float*) alloc((size_t)64*4096*sizeof(float));
  float*  embed  = (float*) alloc((size_t)64*4096*sizeof(float));
  float*  pooled = (float*) alloc(512*sizeof(float));
  float*  sig_sm = (float*) alloc(4096*sizeof(float));
  float*  sig_cm = (float*) alloc(512*sizeof(float));

  k_prep<<<1536, 256, 0, stream>>>(x_in, Wq, Wk, Wv, Wout, xb, Wqb, Wkb, Wvb, Woutb);
  k_qkv<<<dim3(256,3), 256, 0, stream>>>(xb, Wqb, Wkb, Wvb, scale, q_bf, k_bf, vTb);
  hipMemsetAsync(pooled, 0, 512*sizeof(float), stream);
  k_attn<<<dim3(64,8), 256, 0, stream>>>(q_bf, k_bf, vTb, att_bf, pooled);
  k_conv<<<512, 256, 0, stream>>>(vTb, dw_w, dw_b, dw_g, dw_bt, dw_m, dw_v, conv_x);
  k_spatial<<<256, 256, 0, stream>>>(conv_x, si_w1, si_b1, si_g, si_bt, si_m, si_v,
                                     si_w2, si_b2, sig_sm);
  k_channel<<<1, 256, 0, stream>>>(pooled, ci_w1, ci_b1, ci_w2, ci_b2, sig_cm);
  k_dwconv64<<<64, 256, 0, stream>>>(x_in, pe_w1, t1, 1);
  k_dwconv64<<<64, 256, 0, stream>>>(t1, pe_w2, embed, 0);
  k_final<<<256, 64, 0, stream>>>(att_bf, conv_x, sig_sm, sig_cm, Woutb, bout, embed, out);
}